// Round 1
// baseline (11.177 us; speedup 1.0000x reference)
//
#include <hip/hip_runtime.h>

// ResizeToSameSize: 12 fp32 planes -> (1,12,352,352) concat.
// out[c][y][x] = src_c[y >> shift_c][x >> shift_c]; shift_c in {0..5}.
// All scales are powers of two (352 / {352,176,88,44,22,11} = {1,2,4,8,16,32}).

#define TARGET 352
#define PLANE (TARGET * TARGET)   // 123904

struct Ptrs { const float* p[12]; };

__global__ __launch_bounds__(256) void resize_cat_kernel(Ptrs ptrs, float* __restrict__ out) {
    const int c = blockIdx.y;                                   // channel 0..11, wave-uniform
    const int t = blockIdx.x * blockDim.x + threadIdx.x;        // float4 index within plane
    const int e = t * 4;                                        // element index within plane
    const int y = e / TARGET;
    const int x = e - y * TARGET;                               // multiple of 4

    // per-channel metadata (scalar loads, c is uniform per block)
    static const __device__ int d_shift[12] = {0, 1, 2, 3, 4, 5, 1, 2, 3, 4, 5, 1};
    static const __device__ int d_srcsz[12] = {TARGET, 176, 88, 44, 22, 11, 176, 88, 44, 22, 11, 176};

    const int sh = d_shift[c];
    const int s  = d_srcsz[c];
    const float* __restrict__ src = ptrs.p[c];

    float4 v;
    if (sh == 0) {
        // direct copy, 16B coalesced load
        v = *reinterpret_cast<const float4*>(src + e);
    } else {
        const float* row = src + (y >> sh) * s;
        if (sh >= 2) {
            // all 4 output columns map to the same source column
            const float vv = row[x >> sh];
            v = make_float4(vv, vv, vv, vv);
        } else {
            // shift==1: columns pair up (x is a multiple of 4 -> x>>1 even)
            const float a = row[x >> 1];
            const float b = row[(x >> 1) + 1];
            v = make_float4(a, a, b, b);
        }
    }
    *reinterpret_cast<float4*>(out + c * PLANE + e) = v;
}

extern "C" void kernel_launch(void* const* d_in, const int* in_sizes, int n_in,
                              void* d_out, int out_size, void* d_ws, size_t ws_size,
                              hipStream_t stream) {
    Ptrs ptrs;
    for (int i = 0; i < 12; ++i) ptrs.p[i] = (const float*)d_in[i];
    float* out = (float*)d_out;

    // plane float4 count = 123904/4 = 30976 = 121 * 256
    dim3 grid(121, 12);
    resize_cat_kernel<<<grid, 256, 0, stream>>>(ptrs, out);
}

// Round 2
// 10.208 us; speedup vs baseline: 1.0949x; 1.0949x over previous
//
#include <hip/hip_runtime.h>

// ResizeToSameSize: 12 fp32 planes -> (1,12,352,352) concat.
// out[c][y][x] = src_c[y >> shift_c][x >> shift_c]; shift_c in {0..5}.
// Scales are powers of two: 352 / {352,176,88,44,22,11} = {1,2,4,8,16,32}.
//
// Channel-grouped layout: each thread owns one float4-position (y, x..x+3) and
// writes it for 4 channels (blockIdx.y = group 0..2). Shifts/sizes are
// compile-time per group -> straight-line code, no tables, no branches.

#define TARGET 352
#define PLANE (TARGET * TARGET)   // 123904 elements per channel

struct Ptrs { const float* p[12]; };

template <int SH, int SRCSZ>
__device__ __forceinline__ float4 fetch(const float* __restrict__ src, int e, int y, int x) {
    if constexpr (SH == 0) {
        return *reinterpret_cast<const float4*>(src + e);     // 16B coalesced copy
    } else if constexpr (SH == 1) {
        const float* row = src + (y >> 1) * SRCSZ;
        const float a = row[x >> 1];
        const float b = row[(x >> 1) + 1];
        return make_float4(a, a, b, b);
    } else {
        const float* row = src + (y >> SH) * SRCSZ;
        const float v = row[x >> SH];                         // 4 out-cols -> 1 src col
        return make_float4(v, v, v, v);
    }
}

// channel -> (shift, srcsz):
// c:  0    1    2   3   4   5   6    7   8   9   10  11
// sz: 352  176  88  44  22  11  176  88  44  22  11  176
// sh: 0    1    2   3   4   5   1    2   3   4   5   1

__global__ __launch_bounds__(256) void resize_cat_kernel(Ptrs ptrs, float* __restrict__ out) {
    const int g = blockIdx.y;                                 // channel group 0..2
    const int t = blockIdx.x * blockDim.x + threadIdx.x;      // float4 index in plane
    const int e = t * 4;                                      // element index in plane
    const int y = e / TARGET;
    const int x = e - y * TARGET;                             // multiple of 4

    float4 v0, v1, v2, v3;
    if (g == 0) {
        v0 = fetch<0, TARGET>(ptrs.p[0], e, y, x);
        v1 = fetch<1, 176  >(ptrs.p[1], e, y, x);
        v2 = fetch<2, 88   >(ptrs.p[2], e, y, x);
        v3 = fetch<3, 44   >(ptrs.p[3], e, y, x);
    } else if (g == 1) {
        v0 = fetch<4, 22   >(ptrs.p[4], e, y, x);
        v1 = fetch<5, 11   >(ptrs.p[5], e, y, x);
        v2 = fetch<1, 176  >(ptrs.p[6], e, y, x);
        v3 = fetch<2, 88   >(ptrs.p[7], e, y, x);
    } else {
        v0 = fetch<3, 44   >(ptrs.p[8], e, y, x);
        v1 = fetch<4, 22   >(ptrs.p[9], e, y, x);
        v2 = fetch<5, 11   >(ptrs.p[10], e, y, x);
        v3 = fetch<1, 176  >(ptrs.p[11], e, y, x);
    }

    float* base = out + g * 4 * PLANE + e;
    *reinterpret_cast<float4*>(base + 0 * PLANE) = v0;
    *reinterpret_cast<float4*>(base + 1 * PLANE) = v1;
    *reinterpret_cast<float4*>(base + 2 * PLANE) = v2;
    *reinterpret_cast<float4*>(base + 3 * PLANE) = v3;
}

extern "C" void kernel_launch(void* const* d_in, const int* in_sizes, int n_in,
                              void* d_out, int out_size, void* d_ws, size_t ws_size,
                              hipStream_t stream) {
    Ptrs ptrs;
    for (int i = 0; i < 12; ++i) ptrs.p[i] = (const float*)d_in[i];
    float* out = (float*)d_out;

    // plane float4 count = 123904/4 = 30976 = 121 * 256; 3 groups of 4 channels
    dim3 grid(121, 3);
    resize_cat_kernel<<<grid, 256, 0, stream>>>(ptrs, out);
}